// Round 10
// baseline (261.748 us; speedup 1.0000x reference)
//
#include <hip/hip_runtime.h>
#include <stdint.h>

// MLP_tcnn: x(524288x64) -> [W0 64x128 relu] -> [W1..W4 128x128 relu] -> [W5 128x16] + bias
// R10: software-pipelined A-feed on R9's clean base.
//  - R9 (106us, MfmaUtil 30): per-group {8 ds_read -> wait -> 32 MFMA -> sched_barrier}
//    serializes read latency with compute inside each wave; 2 waves/SIMD can't cover it.
//  - Now: half-groups of 4 frags, one-half lookahead, two NAMED buffers A0/A1 (static
//    indexing), each pinned stage = {LD next half ; 16 MFMA current half ; sched_barrier}.
//    Prefetch chain crosses layer boundaries (A depends only on Wlds), so pack_relu's
//    VALU also hides read latency.  Pressure cap kept: peak ~116 arch + 128 acc = 244.
//  - zero_acc eliminated: first-kt MFMA of each layer uses one shared zero floatx4 as
//    C-in (saves ~750 VALU inst/wave).
// Base structure unchanged: whole 148KB frag-linear weight image in LDS (staged once),
// conflict-free static ds_read_b128, lane-local kappa B-frags, 1024 blocks x 8 waves,
// one 64-sample tile per wave, no main-loop barriers.

typedef __bf16 bf16x8 __attribute__((ext_vector_type(8)));
typedef float  floatx4 __attribute__((ext_vector_type(4)));

#define GAS __attribute__((address_space(1)))
#define LAS __attribute__((address_space(3)))

constexpr int NS   = 524288;           // samples
constexpr int SPW  = 64;               // samples per wave-tile
constexpr int NBLK = NS / (8 * SPW);   // 1024 blocks, 8 waves each, ONE tile per wave

// weight image in 16B chunks inside d_ws, FRAG-LINEAR (frag = rb*KT + kt; 64 lanes x 16B):
// A-frag lane l, elem e = W[in = kappa(32kt+8*(l>>4)+e)][out = 16rb+(l&15)]
// L0 (K=64, kappa=identity on input): frag = ot*2+kt (16 frags); L1-4: frag = ot*4+kt
// (32 frags each, frag-bases 16/48/80/112); L5: frags 144+kt (4).
constexpr int WTOT = 9472;             // total chunks = 151552 bytes

__device__ __host__ __forceinline__ int kappa(int s) {
  // s = 32*kt + 8*g + e  ->  feature 32*kt + 16*((e>>2)) + 4*g + (e&3)
  return 32 * (s >> 5) + 16 * ((s >> 2) & 1) + 4 * ((s >> 3) & 3) + (s & 3);
}

__global__ void prep_weights(const float* __restrict__ W0, const float* __restrict__ W1,
                             const float* __restrict__ W2, const float* __restrict__ W3,
                             const float* __restrict__ W4, const float* __restrict__ W5,
                             bf16x8* __restrict__ ws) {
  int gid = blockIdx.x * blockDim.x + threadIdx.x;
  if (gid >= WTOT) return;
  const float* Wsrc; int nout, kt_n, base, ident;
  if (gid < 1024)      { Wsrc = W0; nout = 128; kt_n = 2; base = 0;    ident = 1; }
  else if (gid < 3072) { Wsrc = W1; nout = 128; kt_n = 4; base = 1024; ident = 0; }
  else if (gid < 5120) { Wsrc = W2; nout = 128; kt_n = 4; base = 3072; ident = 0; }
  else if (gid < 7168) { Wsrc = W3; nout = 128; kt_n = 4; base = 5120; ident = 0; }
  else if (gid < 9216) { Wsrc = W4; nout = 128; kt_n = 4; base = 7168; ident = 0; }
  else                 { Wsrc = W5; nout = 16;  kt_n = 4; base = 9216; ident = 0; }
  int id   = gid - base;
  int lane = id & 63;
  int frag = id >> 6;
  int kt   = frag % kt_n;
  int rb   = frag / kt_n;
  int outf = rb * 16 + (lane & 15);
  int gg   = lane >> 4;
  bf16x8 v;
#pragma unroll
  for (int e = 0; e < 8; ++e) {
    int s  = 32 * kt + 8 * gg + e;           // k-slot
    int in = ident ? s : kappa(s);           // logical input feature at this slot
    v[e] = (__bf16)Wsrc[in * nout + outf];
  }
  ws[gid] = v;
}

// acc (C layout) -> B-frags for the next layer under kappa: pure lane-local relu+pack.
__device__ __forceinline__ void pack_relu(const floatx4 acc[8][4], bf16x8 B[4][4]) {
#pragma unroll
  for (int kt = 0; kt < 4; ++kt)
#pragma unroll
    for (int i = 0; i < 4; ++i) {
      floatx4 u = acc[2 * kt][i], v = acc[2 * kt + 1][i];
      bf16x8 b;
      b[0] = (__bf16)fmaxf(u[0], 0.f); b[1] = (__bf16)fmaxf(u[1], 0.f);
      b[2] = (__bf16)fmaxf(u[2], 0.f); b[3] = (__bf16)fmaxf(u[3], 0.f);
      b[4] = (__bf16)fmaxf(v[0], 0.f); b[5] = (__bf16)fmaxf(v[1], 0.f);
      b[6] = (__bf16)fmaxf(v[2], 0.f); b[7] = (__bf16)fmaxf(v[3], 0.f);
      B[kt][i] = b;
    }
}

// pinned pipeline stage helpers (all offsets literal at expansion site)
#define SB __builtin_amdgcn_sched_barrier(0)
#define LDH(buf, fb, fs) do {                      \
    buf[0] = Wlds[(fb) * 64 + lane];               \
    buf[1] = Wlds[((fb) + (fs)) * 64 + lane];      \
    buf[2] = Wlds[((fb) + 2 * (fs)) * 64 + lane];  \
    buf[3] = Wlds[((fb) + 3 * (fs)) * 64 + lane];  \
  } while (0)
#define MMZ(buf, kt, oh) do {                                                             \
    _Pragma("unroll") for (int j = 0; j < 4; ++j) {                                       \
      _Pragma("unroll") for (int i = 0; i < 4; ++i)                                       \
        acc[(oh) * 4 + j][i] =                                                            \
            __builtin_amdgcn_mfma_f32_16x16x32_bf16(buf[j], B[kt][i], z, 0, 0, 0);        \
    }                                                                                     \
  } while (0)
#define MMA(buf, kt, oh) do {                                                             \
    _Pragma("unroll") for (int j = 0; j < 4; ++j) {                                       \
      _Pragma("unroll") for (int i = 0; i < 4; ++i)                                       \
        acc[(oh) * 4 + j][i] = __builtin_amdgcn_mfma_f32_16x16x32_bf16(                   \
            buf[j], B[kt][i], acc[(oh) * 4 + j][i], 0, 0, 0);                             \
    }                                                                                     \
  } while (0)
// hidden layer (KT=4), entering with A0 = this layer's half (kt0,oh0); exits with
// A0 = next half-group at (NB, NS_).  Half bases: (kt,oh) -> Fb + oh*16 + kt.
#define HLAYER(Fb, NB, NS_) do {                   \
    LDH(A1, (Fb) + 16, 4); MMZ(A0, 0, 0); SB;      \
    LDH(A0, (Fb) + 1,  4); MMZ(A1, 0, 1); SB;      \
    LDH(A1, (Fb) + 17, 4); MMA(A0, 1, 0); SB;      \
    LDH(A0, (Fb) + 2,  4); MMA(A1, 1, 1); SB;      \
    LDH(A1, (Fb) + 18, 4); MMA(A0, 2, 0); SB;      \
    LDH(A0, (Fb) + 3,  4); MMA(A1, 2, 1); SB;      \
    LDH(A1, (Fb) + 19, 4); MMA(A0, 3, 0); SB;      \
    LDH(A0, (NB), (NS_)); MMA(A1, 3, 1); SB;       \
  } while (0)

__global__ void __launch_bounds__(512, 2) mlp_kernel(const float* __restrict__ x,
                                                     const float* __restrict__ bias,
                                                     const bf16x8* __restrict__ wimg,
                                                     float* __restrict__ out) {
  __shared__ bf16x8 Wlds[WTOT];        // 151552 B: entire frag-linear weight image

  const int t    = threadIdx.x;
  const int lane = t & 63;
  const int l15  = lane & 15;
  const int g    = lane >> 4;
  const int w    = __builtin_amdgcn_readfirstlane(t >> 6);     // wave 0..7 (SGPR)

  // ---- stage all weights -> LDS (once). Identity copy: per-wave 64-chunk slabs. ----
#pragma unroll
  for (int r = 0; r < 19; ++r) {
    int base = r * 512 + w * 64;
    if (base < WTOT)
      __builtin_amdgcn_global_load_lds((const GAS void*)(wimg + base + lane),
                                       (LAS void*)(Wlds + base), 16, 0, 0);
  }
  __syncthreads();   // drains vmcnt; only barrier in the kernel

  const int wid = __builtin_amdgcn_readfirstlane(blockIdx.x * 8 + w);  // 0..8191
  const size_t sbase = (size_t)wid * SPW;    // this wave's 64 samples (SGPR)

  bf16x8  B[4][4];     // B-frags: [kt][i], sample 16i+l15, k-slots 8g..8g+7 of chunk kt
  floatx4 acc[8][4];   // C: out-feature 16ot+4g+j, sample 16i+l15
  bf16x8  A0[4], A1[4];
  floatx4 z = {0.f, 0.f, 0.f, 0.f};    // shared C-in for each layer's kt=0 MFMAs

  // prologue: start the A-prefetch chain (L0 half (kt0,oh0): bases 0,2,4,6)
  LDH(A0, 0, 2);

  // ---- load x tile directly into B-frag layout (natural feature order) ----
  const float* xw = x + sbase * 64;
#pragma unroll
  for (int kt = 0; kt < 2; ++kt)
#pragma unroll
    for (int i = 0; i < 4; ++i) {
      const floatx4* p = (const floatx4*)(xw + (16 * i + l15) * 64 + 32 * kt + 8 * g);
      floatx4 lo = p[0], hi = p[1];
      bf16x8 v;
      v[0] = (__bf16)lo[0]; v[1] = (__bf16)lo[1]; v[2] = (__bf16)lo[2]; v[3] = (__bf16)lo[3];
      v[4] = (__bf16)hi[0]; v[5] = (__bf16)hi[1]; v[6] = (__bf16)hi[2]; v[7] = (__bf16)hi[3];
      B[kt][i] = v;
    }

  // ---- layer 0: K=64 (halves: (0,0)->0, (0,1)->8, (1,0)->1, (1,1)->9; stride 2) ----
  LDH(A1, 8, 2);  MMZ(A0, 0, 0); SB;
  LDH(A0, 1, 2);  MMZ(A1, 0, 1); SB;
  LDH(A1, 9, 2);  MMA(A0, 1, 0); SB;
  LDH(A0, 16, 4); MMA(A1, 1, 1); SB;      // prefetch L1's (kt0,oh0)
  pack_relu(acc, B);

  // ---- layers 1..4: K=128, prefetch chain continues across pack_relu ----
  HLAYER(16,  48, 4);  pack_relu(acc, B);
  HLAYER(48,  80, 4);  pack_relu(acc, B);
  HLAYER(80, 112, 4);  pack_relu(acc, B);
  HLAYER(112, 144, 1); pack_relu(acc, B);   // exit: A0 = W5 frags 144..147 (kt 0..3)

  // ---- layer 5: M=16, K=128, no relu, + bias, fp32 store ----
  floatx4 o[4];
#pragma unroll
  for (int i = 0; i < 4; ++i)
    o[i] = __builtin_amdgcn_mfma_f32_16x16x32_bf16(A0[0], B[0][i], z, 0, 0, 0);
#pragma unroll
  for (int kt = 1; kt < 4; ++kt)
#pragma unroll
    for (int i = 0; i < 4; ++i)
      o[i] = __builtin_amdgcn_mfma_f32_16x16x32_bf16(A0[kt], B[kt][i], o[i], 0, 0, 0);

  floatx4 bv = *(const floatx4*)(bias + 4 * g);
  floatx4* outv = (floatx4*)out;
#pragma unroll
  for (int i = 0; i < 4; ++i) {
    size_t s = sbase + 16 * i + l15;
    outv[s * 4 + g] = o[i] + bv;    // coalesced: 16 samples x 64B contiguous per i
  }
}

extern "C" void kernel_launch(void* const* d_in, const int* in_sizes, int n_in,
                              void* d_out, int out_size, void* d_ws, size_t ws_size,
                              hipStream_t stream) {
  (void)in_sizes; (void)n_in; (void)out_size; (void)ws_size;
  const float* x    = (const float*)d_in[0];
  const float* W0   = (const float*)d_in[1];
  const float* W1   = (const float*)d_in[2];
  const float* W2   = (const float*)d_in[3];
  const float* W3   = (const float*)d_in[4];
  const float* W4   = (const float*)d_in[5];
  const float* W5   = (const float*)d_in[6];
  const float* bias = (const float*)d_in[7];
  bf16x8* ws = (bf16x8*)d_ws;   // needs 151552 B

  prep_weights<<<(WTOT + 255) / 256, 256, 0, stream>>>(W0, W1, W2, W3, W4, W5, ws);
  mlp_kernel<<<NBLK, 512, 0, stream>>>(x, bias, (const bf16x8*)ws, (float*)d_out);
}

// Round 11
// 251.644 us; speedup vs baseline: 1.0402x; 1.0402x over previous
//
#include <hip/hip_runtime.h>
#include <stdint.h>

// MLP_tcnn: x(524288x64) -> [W0 64x128 relu] -> [W1..W4 128x128 relu] -> [W5 128x16] + bias
// R11: manual counted-lgkmcnt A-feed pipeline on R9/R10's clean base.
//  - R9==R10 (106/112us, Mfma 30%) despite big instruction-mix differences => shared
//    stall floor: lockstep 8-wave ds_read bursts + (likely) compiler lgkmcnt(0) drains.
//  - Now: inline-asm ds_read_b128 (opaque to compiler waitcnt insertion) + explicit
//    s_waitcnt lgkmcnt(4) + sched_barrier(0) (rule-18), 2-stage lookahead ring of 4
//    named 2-frag buffers.  74 half-stages: {2 reads for n+2 ; lgkmcnt(4) ; SB ; 8 MFMA}.
//    Loads get ~600cyc of MFMA to complete -> zero exposed LDS latency even in lockstep.
//  - Counted-wait safety: extra lgkm ops (smem/flat) only make waits MORE conservative.
// Base: whole 148KB frag-linear weight image in LDS, lane-local kappa B-frags, no
// activation LDS, 1024 blocks x 8 waves, one 64-sample tile/wave, launch_bounds(512,2).

typedef __bf16 bf16x8 __attribute__((ext_vector_type(8)));
typedef float  floatx4 __attribute__((ext_vector_type(4)));

#define GAS __attribute__((address_space(1)))
#define LAS __attribute__((address_space(3)))

constexpr int NS   = 524288;           // samples
constexpr int SPW  = 64;               // samples per wave-tile
constexpr int NBLK = NS / (8 * SPW);   // 1024 blocks, 8 waves each, ONE tile per wave

// weight image in 16B chunks, FRAG-LINEAR: frag = ot*KT + kt (ot = out-feature/16).
// A-frag lane l, elem e = W[in = kappa(32kt+8*(l>>4)+e)][out = 16*ot+(l&15)]
// L0 (K=64, KT=2, identity kappa): frags 0..15; L1-4 (KT=4): 16+32l ..; L5: 144..147.
constexpr int WTOT = 9472;             // total chunks = 151552 bytes

__device__ __host__ __forceinline__ int kappa(int s) {
  return 32 * (s >> 5) + 16 * ((s >> 2) & 1) + 4 * ((s >> 3) & 3) + (s & 3);
}

__global__ void prep_weights(const float* __restrict__ W0, const float* __restrict__ W1,
                             const float* __restrict__ W2, const float* __restrict__ W3,
                             const float* __restrict__ W4, const float* __restrict__ W5,
                             bf16x8* __restrict__ ws) {
  int gid = blockIdx.x * blockDim.x + threadIdx.x;
  if (gid >= WTOT) return;
  const float* Wsrc; int nout, kt_n, base, ident;
  if (gid < 1024)      { Wsrc = W0; nout = 128; kt_n = 2; base = 0;    ident = 1; }
  else if (gid < 3072) { Wsrc = W1; nout = 128; kt_n = 4; base = 1024; ident = 0; }
  else if (gid < 5120) { Wsrc = W2; nout = 128; kt_n = 4; base = 3072; ident = 0; }
  else if (gid < 7168) { Wsrc = W3; nout = 128; kt_n = 4; base = 5120; ident = 0; }
  else if (gid < 9216) { Wsrc = W4; nout = 128; kt_n = 4; base = 7168; ident = 0; }
  else                 { Wsrc = W5; nout = 16;  kt_n = 4; base = 9216; ident = 0; }
  int id   = gid - base;
  int lane = id & 63;
  int frag = id >> 6;
  int kt   = frag % kt_n;
  int rb   = frag / kt_n;
  int outf = rb * 16 + (lane & 15);
  int gg   = lane >> 4;
  bf16x8 v;
#pragma unroll
  for (int e = 0; e < 8; ++e) {
    int s  = 32 * kt + 8 * gg + e;
    int in = ident ? s : kappa(s);
    v[e] = (__bf16)Wsrc[in * nout + outf];
  }
  ws[gid] = v;
}

__device__ __forceinline__ bf16x8 asb(floatx4 v) {
  union { floatx4 f; bf16x8 b; } u; u.f = v; return u.b;
}

// acc (C layout) -> B-frags for next layer under kappa: pure lane-local relu+pack.
__device__ __forceinline__ void pack_relu(const floatx4 acc[8][4], bf16x8 B[4][4]) {
#pragma unroll
  for (int kt = 0; kt < 4; ++kt)
#pragma unroll
    for (int i = 0; i < 4; ++i) {
      floatx4 u = acc[2 * kt][i], v = acc[2 * kt + 1][i];
      bf16x8 b;
      b[0] = (__bf16)fmaxf(u[0], 0.f); b[1] = (__bf16)fmaxf(u[1], 0.f);
      b[2] = (__bf16)fmaxf(u[2], 0.f); b[3] = (__bf16)fmaxf(u[3], 0.f);
      b[4] = (__bf16)fmaxf(v[0], 0.f); b[5] = (__bf16)fmaxf(v[1], 0.f);
      b[6] = (__bf16)fmaxf(v[2], 0.f); b[7] = (__bf16)fmaxf(v[3], 0.f);
      B[kt][i] = b;
    }
}

#define SB __builtin_amdgcn_sched_barrier(0)
// inline-asm ds_read_b128: opaque to compiler waitcnt insertion (manual lgkmcnt control)
#define DSR(dst, f) asm volatile("ds_read_b128 %0, %1 offset:%c2"                      \
    : "=v"(dst) : "v"((f) < 64 ? a0 : (f) < 128 ? a1 : a2), "i"((((f) & 63) * 1024)))
#define WAITK(n) asm volatile("s_waitcnt lgkmcnt(" #n ")")
#define MM4Z(buf, kt, j) do { _Pragma("unroll") for (int i = 0; i < 4; ++i)            \
    acc[j][i] = __builtin_amdgcn_mfma_f32_16x16x32_bf16(asb(buf), B[kt][i], z, 0, 0, 0); } while (0)
#define MM4A(buf, kt, j) do { _Pragma("unroll") for (int i = 0; i < 4; ++i)            \
    acc[j][i] = __builtin_amdgcn_mfma_f32_16x16x32_bf16(asb(buf), B[kt][i], acc[j][i], 0, 0, 0); } while (0)
// half-stage: issue 2 reads for stage n+2 into ring buf bl; wait until stage n's 2 reads
// retired (4 younger stay in flight); MFMA stage n from ring buf bm (rows j0, j0+1).
#define STZ(bm, bl, f1, f2, kt, j0) \
  DSR(bl##a, f1); DSR(bl##b, f2); WAITK(4); SB; MM4Z(bm##a, kt, j0); MM4Z(bm##b, kt, (j0) + 1)
#define STA(bm, bl, f1, f2, kt, j0) \
  DSR(bl##a, f1); DSR(bl##b, f2); WAITK(4); SB; MM4A(bm##a, kt, j0); MM4A(bm##b, kt, (j0) + 1)

// hidden layer (KT=4, frag base F): 16 half-stages, ring phase 0 at entry.
// seq[m]: kt=m>>2, oh=(m>>1)&1, h=m&1; f1 = F+(4oh+2h)*4+kt, f2 = f1+4.
// Last 2 stages prefetch next layer's seq0/seq1 = (T1a,T1b),(T2a,T2b).
#define HLAYER(F, T1a, T1b, T2a, T2b) do {        \
    STZ(b0, b2, (F)+16, (F)+20, 0, 0);            \
    STZ(b1, b3, (F)+24, (F)+28, 0, 2);            \
    STZ(b2, b0, (F)+1,  (F)+5,  0, 4);            \
    STZ(b3, b1, (F)+9,  (F)+13, 0, 6);            \
    STA(b0, b2, (F)+17, (F)+21, 1, 0);            \
    STA(b1, b3, (F)+25, (F)+29, 1, 2);            \
    STA(b2, b0, (F)+2,  (F)+6,  1, 4);            \
    STA(b3, b1, (F)+10, (F)+14, 1, 6);            \
    STA(b0, b2, (F)+18, (F)+22, 2, 0);            \
    STA(b1, b3, (F)+26, (F)+30, 2, 2);            \
    STA(b2, b0, (F)+3,  (F)+7,  2, 4);            \
    STA(b3, b1, (F)+11, (F)+15, 2, 6);            \
    STA(b0, b2, (F)+19, (F)+23, 3, 0);            \
    STA(b1, b3, (F)+27, (F)+31, 3, 2);            \
    STA(b2, b0, (T1a),  (T1b),  3, 4);            \
    STA(b3, b1, (T2a),  (T2b),  3, 6);            \
  } while (0)

__global__ void __launch_bounds__(512, 2) mlp_kernel(const float* __restrict__ x,
                                                     const float* __restrict__ bias,
                                                     const bf16x8* __restrict__ wimg,
                                                     float* __restrict__ out) {
  __shared__ bf16x8 Wlds[WTOT];        // 151552 B: entire frag-linear weight image

  const int t    = threadIdx.x;
  const int lane = t & 63;
  const int l15  = lane & 15;
  const int g    = lane >> 4;
  const int w    = __builtin_amdgcn_readfirstlane(t >> 6);     // wave 0..7 (SGPR)

  // ---- stage all weights -> LDS (once per block) ----
#pragma unroll
  for (int r = 0; r < 19; ++r) {
    int base = r * 512 + w * 64;
    if (base < WTOT)
      __builtin_amdgcn_global_load_lds((const GAS void*)(wimg + base + lane),
                                       (LAS void*)(Wlds + base), 16, 0, 0);
  }
  __syncthreads();   // drains vmcnt+lgkm; Wlds ready; only block barrier

  // LDS byte addresses for asm ds_read (offset field is 16-bit: 3 region bases)
  const uint32_t a0 = (uint32_t)(uintptr_t)((LAS void*)Wlds) + (uint32_t)lane * 16u;
  const uint32_t a1 = a0 + 65536u;
  const uint32_t a2 = a0 + 131072u;

  const int wid = __builtin_amdgcn_readfirstlane(blockIdx.x * 8 + w);  // 0..8191
  const size_t sbase = (size_t)wid * SPW;

  bf16x8  B[4][4];      // [kt][i]: sample 16i+l15, k-slots 8g..8g+7 of chunk kt
  floatx4 acc[8][4];    // C: out-feature 16*j+4g+e, sample 16i+l15
  floatx4 b0a, b0b, b1a, b1b, b2a, b2b, b3a, b3b;   // 2-frag ring buffers
  const floatx4 z = {0.f, 0.f, 0.f, 0.f};

  // ---- x tile -> B-frag layout (global loads; long latency overlaps prologue) ----
  const GAS float* xw = (const GAS float*)x + sbase * 64;
#pragma unroll
  for (int kt = 0; kt < 2; ++kt)
#pragma unroll
    for (int i = 0; i < 4; ++i) {
      const GAS floatx4* p = (const GAS floatx4*)(xw + (16 * i + l15) * 64 + 32 * kt + 8 * g);
      floatx4 lo = p[0], hi = p[1];
      bf16x8 v;
      v[0] = (__bf16)lo[0]; v[1] = (__bf16)lo[1]; v[2] = (__bf16)lo[2]; v[3] = (__bf16)lo[3];
      v[4] = (__bf16)hi[0]; v[5] = (__bf16)hi[1]; v[6] = (__bf16)hi[2]; v[7] = (__bf16)hi[3];
      B[kt][i] = v;
    }

  // ---- prologue: preload L0 seq0 (frags 0,2) and seq1 (4,6) ----
  DSR(b0a, 0); DSR(b0b, 2);
  DSR(b1a, 4); DSR(b1b, 6);

  // ---- layer 0 (K=64, KT=2, frags 0..15): 8 half-stages ----
  STZ(b0, b2, 8, 10, 0, 0);      // MFMA seq0 (rows 0,1 kt0); load seq2
  STZ(b1, b3, 12, 14, 0, 2);     // seq1 (rows 2,3); load seq3
  STZ(b2, b0, 1, 3, 0, 4);       // seq2 (rows 4,5); load seq4
  STZ(b3, b1, 5, 7, 0, 6);       // seq3 (rows 6,7); load seq5
  STA(b0, b2, 9, 11, 1, 0);      // seq4 (rows 0,1 kt1); load seq6
  STA(b1, b3, 13, 15, 1, 2);     // seq5; load seq7
  STA(b2, b0, 16, 20, 1, 4);     // seq6; load L1 seq0
  STA(b3, b1, 24, 28, 1, 6);     // seq7; load L1 seq1
  pack_relu(acc, B);

  // ---- layers 1..4 (K=128): prefetch chain crosses layer boundaries ----
  HLAYER(16,  48, 52, 56, 60);   pack_relu(acc, B);
  HLAYER(48,  80, 84, 88, 92);   pack_relu(acc, B);
  HLAYER(80, 112, 116, 120, 124); pack_relu(acc, B);
  HLAYER(112, 144, 145, 146, 147); pack_relu(acc, B);

  // ---- layer 5 (M=16, K=128, frags 144..147, no relu) ----
  floatx4 o[4];
  WAITK(2); SB;                  // b0 (144,145) retired; b1 (146,147) in flight
#pragma unroll
  for (int i = 0; i < 4; ++i)
    o[i] = __builtin_amdgcn_mfma_f32_16x16x32_bf16(asb(b0a), B[0][i], z, 0, 0, 0);
#pragma unroll
  for (int i = 0; i < 4; ++i)
    o[i] = __builtin_amdgcn_mfma_f32_16x16x32_bf16(asb(b0b), B[1][i], o[i], 0, 0, 0);
  WAITK(0); SB;
#pragma unroll
  for (int i = 0; i < 4; ++i)
    o[i] = __builtin_amdgcn_mfma_f32_16x16x32_bf16(asb(b1a), B[2][i], o[i], 0, 0, 0);
#pragma unroll
  for (int i = 0; i < 4; ++i)
    o[i] = __builtin_amdgcn_mfma_f32_16x16x32_bf16(asb(b1b), B[3][i], o[i], 0, 0, 0);

  floatx4 bv = *(const floatx4*)(bias + 4 * g);
  floatx4* outv = (floatx4*)out;
#pragma unroll
  for (int i = 0; i < 4; ++i) {
    size_t s = sbase + 16 * i + l15;
    outv[s * 4 + g] = o[i] + bv;    // coalesced: 16 samples x 64B contiguous per i
  }
}

extern "C" void kernel_launch(void* const* d_in, const int* in_sizes, int n_in,
                              void* d_out, int out_size, void* d_ws, size_t ws_size,
                              hipStream_t stream) {
  (void)in_sizes; (void)n_in; (void)out_size; (void)ws_size;
  const float* x    = (const float*)d_in[0];
  const float* W0   = (const float*)d_in[1];
  const float* W1   = (const float*)d_in[2];
  const float* W2   = (const float*)d_in[3];
  const float* W3   = (const float*)d_in[4];
  const float* W4   = (const float*)d_in[5];
  const float* W5   = (const float*)d_in[6];
  const float* bias = (const float*)d_in[7];
  bf16x8* ws = (bf16x8*)d_ws;   // needs 151552 B

  prep_weights<<<(WTOT + 255) / 256, 256, 0, stream>>>(W0, W1, W2, W3, W4, W5, ws);
  mlp_kernel<<<NBLK, 512, 0, stream>>>(x, bias, (const bf16x8*)ws, (float*)d_out);
}